// Round 3
// baseline (3485.774 us; speedup 1.0000x reference)
//
#include <hip/hip_runtime.h>
#include <math.h>

#define B 2048
#define C 1024
#define NBLK 256   // persistent grid == CU count; 1 block/CU guarantees co-residency

typedef _Float16 v2h __attribute__((ext_vector_type(2)));

// ---------------------------------------------------------------------------
// Kernel 1: row softmax of y/2 for both inputs -> fp16 output. (unchanged)
// ---------------------------------------------------------------------------
__global__ __launch_bounds__(256) void softmax_k(const float* __restrict__ ys,
                                                 const float* __restrict__ yt,
                                                 _Float16* __restrict__ ps,
                                                 _Float16* __restrict__ pt) {
    int b = blockIdx.x;
    const float* in;
    _Float16* out;
    if (b < B) { in = ys + (size_t)b * C;        out = ps + (size_t)b * C; }
    else       { in = yt + (size_t)(b - B) * C;  out = pt + (size_t)(b - B) * C; }
    int tid = threadIdx.x;
    int lane = tid & 63, wave = tid >> 6;

    float4 v = reinterpret_cast<const float4*>(in)[tid];
    v.x *= 0.5f; v.y *= 0.5f; v.z *= 0.5f; v.w *= 0.5f;

    float mx = fmaxf(fmaxf(v.x, v.y), fmaxf(v.z, v.w));
    #pragma unroll
    for (int m = 32; m >= 1; m >>= 1) mx = fmaxf(mx, __shfl_xor(mx, m, 64));
    __shared__ float redm[4];
    if (lane == 0) redm[wave] = mx;
    __syncthreads();
    mx = fmaxf(fmaxf(redm[0], redm[1]), fmaxf(redm[2], redm[3]));

    float4 e;
    e.x = expf(v.x - mx); e.y = expf(v.y - mx);
    e.z = expf(v.z - mx); e.w = expf(v.w - mx);
    float s = e.x + e.y + e.z + e.w;
    #pragma unroll
    for (int m = 32; m >= 1; m >>= 1) s += __shfl_xor(s, m, 64);
    __shared__ float reds[4];
    if (lane == 0) reds[wave] = s;
    __syncthreads();
    s = reds[0] + reds[1] + reds[2] + reds[3];

    float inv = 1.0f / s;
    float2 st;
    v2h* sp = (v2h*)&st;
    sp[0] = (v2h){(_Float16)(e.x * inv), (_Float16)(e.y * inv)};
    sp[1] = (v2h){(_Float16)(e.z * inv), (_Float16)(e.w * inv)};
    reinterpret_cast<float2*>(out)[tid] = st;
}

// ---------------------------------------------------------------------------
// Kernel 2 v3: K[i][j] = exp(20*S - 20), S = sum_c min(ps[i,c], pt[j,c]).
// 512 threads (2 waves/SIMD for latency hiding), 128x128 tile, 4x8 frags.
// fp16 chunk accumulation: 16 pk_min + 16 pk_add per 32 elems, ONE fdot2
// fold per chunk (dot2 appears to be quarter-rate; pk_add is full-rate).
// __launch_bounds__(512,2): cap occupancy target -> acc stays in arch VGPRs.
// ---------------------------------------------------------------------------
__global__ __launch_bounds__(512, 2) void cdist_k(const _Float16* __restrict__ ps,
                                                  const _Float16* __restrict__ pt,
                                                  float* __restrict__ Km) {
    __shared__ __align__(16) v2h As[16][132];
    __shared__ __align__(16) v2h Bs[16][132];
    int tid = threadIdx.x;
    int tx = tid & 15;          // 8-col group (split +-64)
    int ty = tid >> 4;          // [0,32): 4-row group
    int r0 = blockIdx.y * 128, c0 = blockIdx.x * 128;

    float acc[4][8];
    v2h csum[4][8];
    #pragma unroll
    for (int i = 0; i < 4; ++i)
        #pragma unroll
        for (int j = 0; j < 8; ++j) {
            acc[i][j] = 0.f;
            csum[i][j] = (v2h){(_Float16)0.f, (_Float16)0.f};
        }

    int lr = tid >> 2;          // [0,128): staging row
    int lq = tid & 3;           // float4 slot within the 64B chunk
    const float4* pa = reinterpret_cast<const float4*>(ps + (size_t)(r0 + lr) * C);
    const float4* pb = reinterpret_cast<const float4*>(pt + (size_t)(c0 + lr) * C);
    const v2h one2 = {(_Float16)1.0f, (_Float16)1.0f};

    // prefetch ch=0
    float4 a0 = pa[lq];
    float4 b0 = pb[lq];

    for (int ch = 0; ch < 32; ++ch) {
        v2h* ah = (v2h*)&a0;
        v2h* bh = (v2h*)&b0;
        #pragma unroll
        for (int c2 = 0; c2 < 4; ++c2) {
            As[lq * 4 + c2][lr] = ah[c2];
            Bs[lq * 4 + c2][lr] = bh[c2];
        }
        __syncthreads();

        // issue next chunk's loads; latency hides under the k2 compute
        int nch = (ch + 1) & 31;
        float4 na = pa[nch * 4 + lq];
        float4 nb = pb[nch * 4 + lq];

        #pragma unroll
        for (int k2 = 0; k2 < 16; ++k2) {
            v2h a2[4], b2[8];
            *(float4*)&a2[0] = *(const float4*)&As[k2][ty * 4];
            *(float4*)&b2[0] = *(const float4*)&Bs[k2][tx * 4];
            *(float4*)&b2[4] = *(const float4*)&Bs[k2][64 + tx * 4];
            #pragma unroll
            for (int i = 0; i < 4; ++i)
                #pragma unroll
                for (int j = 0; j < 8; ++j)
                    csum[i][j] += __builtin_elementwise_min(a2[i], b2[j]);
        }
        // fold fp16 chunk sums into f32 accumulators (once per 32-elem chunk)
        #pragma unroll
        for (int i = 0; i < 4; ++i)
            #pragma unroll
            for (int j = 0; j < 8; ++j) {
#if __has_builtin(__builtin_amdgcn_fdot2)
                acc[i][j] = __builtin_amdgcn_fdot2(csum[i][j], one2, acc[i][j], false);
#else
                acc[i][j] += (float)csum[i][j].x + (float)csum[i][j].y;
#endif
                csum[i][j] = (v2h){(_Float16)0.f, (_Float16)0.f};
            }
        __syncthreads();
        a0 = na; b0 = nb;
    }

    #pragma unroll
    for (int i = 0; i < 4; ++i) {
        int row = r0 + ty * 4 + i;
        float4 k0, k1;
        k0.x = __expf(20.f * acc[i][0] - 20.f);
        k0.y = __expf(20.f * acc[i][1] - 20.f);
        k0.z = __expf(20.f * acc[i][2] - 20.f);
        k0.w = __expf(20.f * acc[i][3] - 20.f);
        k1.x = __expf(20.f * acc[i][4] - 20.f);
        k1.y = __expf(20.f * acc[i][5] - 20.f);
        k1.z = __expf(20.f * acc[i][6] - 20.f);
        k1.w = __expf(20.f * acc[i][7] - 20.f);
        *reinterpret_cast<float4*>(&Km[(size_t)row * B + c0 + tx * 4]) = k0;
        *reinterpret_cast<float4*>(&Km[(size_t)row * B + c0 + 64 + tx * 4]) = k1;
    }
}

// ---------------------------------------------------------------------------
// Grid barrier: flag-array arrive (parallel release stores), block 0
// aggregates, "go" broadcast. Agent-scope atomics only -> coherent at LLC
// across XCDs (per-XCD L2 never caches these lines).
// ---------------------------------------------------------------------------
__device__ __forceinline__ void gridbar(unsigned* flags, unsigned* go,
                                        int bid, int t0, unsigned phase) {
    __syncthreads();
    if (t0 == 0)
        __hip_atomic_store(&flags[bid], phase, __ATOMIC_RELEASE,
                           __HIP_MEMORY_SCOPE_AGENT);
    if (bid == 0) {
        if (t0 < NBLK) {
            while (__hip_atomic_load(&flags[t0], __ATOMIC_ACQUIRE,
                                     __HIP_MEMORY_SCOPE_AGENT) < phase)
                __builtin_amdgcn_s_sleep(1);
        }
        __syncthreads();
        if (t0 == 0)
            __hip_atomic_store(go, phase, __ATOMIC_RELEASE,
                               __HIP_MEMORY_SCOPE_AGENT);
    }
    if (t0 == 0) {
        while (__hip_atomic_load(go, __ATOMIC_ACQUIRE,
                                 __HIP_MEMORY_SCOPE_AGENT) < phase)
            __builtin_amdgcn_s_sleep(1);
    }
    __syncthreads();
}

// ---------------------------------------------------------------------------
// Kernel 3 v2: persistent Sinkhorn + loss, ZERO atomicAdds in the loop.
// 256 blocks x 1024 threads. Block owns 8 full ROWS (kr: thread = 2 cols of
// each) AND 8 full COLUMNS (kc: thread = 2 rows x 8 cols, gathered once).
// Row phase: block-local reduce -> a (writes 8 agent stores/block).
// Col phase: block-local reduce over owned columns -> s (8 stores/block).
// Two grid barriers per iteration. K is read from HBM exactly once.
// ---------------------------------------------------------------------------
__global__ __launch_bounds__(1024) void sink_k(const float* __restrict__ Km,
                                               float* __restrict__ s,
                                               float* __restrict__ a_glob,
                                               unsigned* __restrict__ flags,
                                               float* __restrict__ out) {
    __shared__ float part[8][16];
    __shared__ float a8[8];
    int t0 = threadIdx.x;
    int lane = t0 & 63, wv = t0 >> 6;
    int bid = blockIdx.x;
    int r0 = bid * 8;          // owned rows
    int c0 = bid * 8;          // owned cols
    int jx = 2 * t0;           // this thread's 2 columns (row phase)
    unsigned* go = flags + NBLK;

    // preload row block: K[r0+i][jx..jx+1]  (coalesced)
    float2 kr[8];
    #pragma unroll
    for (int i = 0; i < 8; ++i)
        kr[i] = *reinterpret_cast<const float2*>(&Km[(size_t)(r0 + i) * B + jx]);

    // preload col block: rows {2*t0, 2*t0+1} x cols c0..c0+7 (gathered)
    float4 kc[4];
    {
        const float4* p0 = reinterpret_cast<const float4*>(&Km[(size_t)(2 * t0) * B + c0]);
        const float4* p1 = reinterpret_cast<const float4*>(&Km[(size_t)(2 * t0 + 1) * B + c0]);
        kc[0] = p0[0]; kc[1] = p0[1];
        kc[2] = p1[0]; kc[3] = p1[1];
    }

    for (int t = 1; t <= 20; ++t) {
        // ---- row phase: a = 1/(K * (1/s)) ----
        float bx = 1.0f, by = 1.0f;
        if (t > 1) {
            bx = 1.0f / __hip_atomic_load(&s[jx], __ATOMIC_ACQUIRE,
                                          __HIP_MEMORY_SCOPE_AGENT);
            by = 1.0f / __hip_atomic_load(&s[jx + 1], __ATOMIC_ACQUIRE,
                                          __HIP_MEMORY_SCOPE_AGENT);
        }
        #pragma unroll
        for (int i = 0; i < 8; ++i) {
            float v = fmaf(kr[i].x, bx, kr[i].y * by);
            #pragma unroll
            for (int m = 32; m >= 1; m >>= 1) v += __shfl_xor(v, m, 64);
            if (lane == 0) part[i][wv] = v;
        }
        __syncthreads();
        if (t0 < 8) {
            float sum = 0.f;
            #pragma unroll
            for (int w = 0; w < 16; ++w) sum += part[t0][w];
            float av = 1.0f / sum;
            a8[t0] = av;
            __hip_atomic_store(&a_glob[r0 + t0], av, __ATOMIC_RELEASE,
                               __HIP_MEMORY_SCOPE_AGENT);
        }
        gridbar(flags, go, bid, t0, (unsigned)(2 * t - 1));

        // ---- col phase: s[c] = sum_i a_i K[i][c]  (owned columns) ----
        float av0 = __hip_atomic_load(&a_glob[2 * t0], __ATOMIC_ACQUIRE,
                                      __HIP_MEMORY_SCOPE_AGENT);
        float av1 = __hip_atomic_load(&a_glob[2 * t0 + 1], __ATOMIC_ACQUIRE,
                                      __HIP_MEMORY_SCOPE_AGENT);
        float p[8];
        #pragma unroll
        for (int c = 0; c < 4; ++c) {
            p[c]     = fmaf(av0, kc[0][c], av1 * kc[2][c]);
            p[4 + c] = fmaf(av0, kc[1][c], av1 * kc[3][c]);
        }
        #pragma unroll
        for (int c = 0; c < 8; ++c) {
            float v = p[c];
            #pragma unroll
            for (int m = 32; m >= 1; m >>= 1) v += __shfl_xor(v, m, 64);
            if (lane == 0) part[c][wv] = v;
        }
        __syncthreads();
        if (t0 < 8) {
            float sum = 0.f;
            #pragma unroll
            for (int w = 0; w < 16; ++w) sum += part[t0][w];
            __hip_atomic_store(&s[c0 + t0], sum, __ATOMIC_RELEASE,
                               __HIP_MEMORY_SCOPE_AGENT);
        }
        gridbar(flags, go, bid, t0, (unsigned)(2 * t));
    }

    // ---- fused loss: -1e-4 * sum_ij a_i K_ij (1/s20_j) ln K_ij ----
    float bx = 1.0f / __hip_atomic_load(&s[jx], __ATOMIC_ACQUIRE,
                                        __HIP_MEMORY_SCOPE_AGENT);
    float by = 1.0f / __hip_atomic_load(&s[jx + 1], __ATOMIC_ACQUIRE,
                                        __HIP_MEMORY_SCOPE_AGENT);
    float acc = 0.f;
    #pragma unroll
    for (int i = 0; i < 8; ++i) {
        float ai = a8[i];   // this block's own rows' a from iteration 20
        acc += ai * (kr[i].x * bx * __logf(kr[i].x) +
                     kr[i].y * by * __logf(kr[i].y));
    }
    #pragma unroll
    for (int m = 32; m >= 1; m >>= 1) acc += __shfl_xor(acc, m, 64);
    if (lane == 0) part[0][wv] = acc;
    __syncthreads();
    if (t0 == 0) {
        float sum = 0.f;
        #pragma unroll
        for (int w = 0; w < 16; ++w) sum += part[0][w];
        atomicAdd(out, -0.1f * 0.001f * sum);
    }
}

// ---------------------------------------------------------------------------
extern "C" void kernel_launch(void* const* d_in, const int* in_sizes, int n_in,
                              void* d_out, int out_size, void* d_ws, size_t ws_size,
                              hipStream_t stream) {
    const float* ys = (const float*)d_in[0];
    const float* yt = (const float*)d_in[1];
    float* out = (float*)d_out;

    char* wsb = (char*)d_ws;
    _Float16* ps = (_Float16*)wsb;                               // 4 MB
    _Float16* pt = (_Float16*)(wsb + (size_t)B * C * 2);         // 4 MB
    float* Km    = (float*)(wsb + (size_t)2 * B * C * 2);        // 16.8 MB
    float* s     = Km + (size_t)B * B;                           // B floats
    float* a_glob = s + B;                                       // B floats
    unsigned* flags = (unsigned*)(a_glob + B);                   // NBLK + 1

    (void)hipMemsetAsync(flags, 0, (NBLK + 1) * sizeof(unsigned), stream);
    (void)hipMemsetAsync(out, 0, sizeof(float), stream);

    softmax_k<<<2 * B, 256, 0, stream>>>(ys, yt, ps, pt);
    cdist_k<<<dim3(16, 16), 512, 0, stream>>>(ps, pt, Km);
    sink_k<<<NBLK, 1024, 0, stream>>>(Km, s, a_glob, flags, out);
}

// Round 4
// 446.949 us; speedup vs baseline: 7.7990x; 7.7990x over previous
//
#include <hip/hip_runtime.h>
#include <math.h>

#define B 2048
#define C 1024
#define NBLK 256   // persistent grid == CU count; 1 block/CU guarantees co-residency

typedef _Float16 v2h __attribute__((ext_vector_type(2)));

// ---------------------------------------------------------------------------
// Kernel 1: row softmax of y/2 for both inputs -> fp16 output. (unchanged)
// ---------------------------------------------------------------------------
__global__ __launch_bounds__(256) void softmax_k(const float* __restrict__ ys,
                                                 const float* __restrict__ yt,
                                                 _Float16* __restrict__ ps,
                                                 _Float16* __restrict__ pt) {
    int b = blockIdx.x;
    const float* in;
    _Float16* out;
    if (b < B) { in = ys + (size_t)b * C;        out = ps + (size_t)b * C; }
    else       { in = yt + (size_t)(b - B) * C;  out = pt + (size_t)(b - B) * C; }
    int tid = threadIdx.x;
    int lane = tid & 63, wave = tid >> 6;

    float4 v = reinterpret_cast<const float4*>(in)[tid];
    v.x *= 0.5f; v.y *= 0.5f; v.z *= 0.5f; v.w *= 0.5f;

    float mx = fmaxf(fmaxf(v.x, v.y), fmaxf(v.z, v.w));
    #pragma unroll
    for (int m = 32; m >= 1; m >>= 1) mx = fmaxf(mx, __shfl_xor(mx, m, 64));
    __shared__ float redm[4];
    if (lane == 0) redm[wave] = mx;
    __syncthreads();
    mx = fmaxf(fmaxf(redm[0], redm[1]), fmaxf(redm[2], redm[3]));

    float4 e;
    e.x = expf(v.x - mx); e.y = expf(v.y - mx);
    e.z = expf(v.z - mx); e.w = expf(v.w - mx);
    float s = e.x + e.y + e.z + e.w;
    #pragma unroll
    for (int m = 32; m >= 1; m >>= 1) s += __shfl_xor(s, m, 64);
    __shared__ float reds[4];
    if (lane == 0) reds[wave] = s;
    __syncthreads();
    s = reds[0] + reds[1] + reds[2] + reds[3];

    float inv = 1.0f / s;
    float2 st;
    v2h* sp = (v2h*)&st;
    sp[0] = (v2h){(_Float16)(e.x * inv), (_Float16)(e.y * inv)};
    sp[1] = (v2h){(_Float16)(e.z * inv), (_Float16)(e.w * inv)};
    reinterpret_cast<float2*>(out)[tid] = st;
}

// ---------------------------------------------------------------------------
// Kernel 2 v3: K[i][j] = exp(20*S - 20), S = sum_c min(ps[i,c], pt[j,c]).
// (byte-identical to round 3 -- isolates the sink_k change)
// ---------------------------------------------------------------------------
__global__ __launch_bounds__(512, 2) void cdist_k(const _Float16* __restrict__ ps,
                                                  const _Float16* __restrict__ pt,
                                                  float* __restrict__ Km) {
    __shared__ __align__(16) v2h As[16][132];
    __shared__ __align__(16) v2h Bs[16][132];
    int tid = threadIdx.x;
    int tx = tid & 15;          // 8-col group (split +-64)
    int ty = tid >> 4;          // [0,32): 4-row group
    int r0 = blockIdx.y * 128, c0 = blockIdx.x * 128;

    float acc[4][8];
    v2h csum[4][8];
    #pragma unroll
    for (int i = 0; i < 4; ++i)
        #pragma unroll
        for (int j = 0; j < 8; ++j) {
            acc[i][j] = 0.f;
            csum[i][j] = (v2h){(_Float16)0.f, (_Float16)0.f};
        }

    int lr = tid >> 2;          // [0,128): staging row
    int lq = tid & 3;           // float4 slot within the 64B chunk
    const float4* pa = reinterpret_cast<const float4*>(ps + (size_t)(r0 + lr) * C);
    const float4* pb = reinterpret_cast<const float4*>(pt + (size_t)(c0 + lr) * C);
    const v2h one2 = {(_Float16)1.0f, (_Float16)1.0f};

    // prefetch ch=0
    float4 a0 = pa[lq];
    float4 b0 = pb[lq];

    for (int ch = 0; ch < 32; ++ch) {
        v2h* ah = (v2h*)&a0;
        v2h* bh = (v2h*)&b0;
        #pragma unroll
        for (int c2 = 0; c2 < 4; ++c2) {
            As[lq * 4 + c2][lr] = ah[c2];
            Bs[lq * 4 + c2][lr] = bh[c2];
        }
        __syncthreads();

        // issue next chunk's loads; latency hides under the k2 compute
        int nch = (ch + 1) & 31;
        float4 na = pa[nch * 4 + lq];
        float4 nb = pb[nch * 4 + lq];

        #pragma unroll
        for (int k2 = 0; k2 < 16; ++k2) {
            v2h a2[4], b2[8];
            *(float4*)&a2[0] = *(const float4*)&As[k2][ty * 4];
            *(float4*)&b2[0] = *(const float4*)&Bs[k2][tx * 4];
            *(float4*)&b2[4] = *(const float4*)&Bs[k2][64 + tx * 4];
            #pragma unroll
            for (int i = 0; i < 4; ++i)
                #pragma unroll
                for (int j = 0; j < 8; ++j)
                    csum[i][j] += __builtin_elementwise_min(a2[i], b2[j]);
        }
        // fold fp16 chunk sums into f32 accumulators (once per 32-elem chunk)
        #pragma unroll
        for (int i = 0; i < 4; ++i)
            #pragma unroll
            for (int j = 0; j < 8; ++j) {
#if __has_builtin(__builtin_amdgcn_fdot2)
                acc[i][j] = __builtin_amdgcn_fdot2(csum[i][j], one2, acc[i][j], false);
#else
                acc[i][j] += (float)csum[i][j].x + (float)csum[i][j].y;
#endif
                csum[i][j] = (v2h){(_Float16)0.f, (_Float16)0.f};
            }
        __syncthreads();
        a0 = na; b0 = nb;
    }

    #pragma unroll
    for (int i = 0; i < 4; ++i) {
        int row = r0 + ty * 4 + i;
        float4 k0, k1;
        k0.x = __expf(20.f * acc[i][0] - 20.f);
        k0.y = __expf(20.f * acc[i][1] - 20.f);
        k0.z = __expf(20.f * acc[i][2] - 20.f);
        k0.w = __expf(20.f * acc[i][3] - 20.f);
        k1.x = __expf(20.f * acc[i][4] - 20.f);
        k1.y = __expf(20.f * acc[i][5] - 20.f);
        k1.z = __expf(20.f * acc[i][6] - 20.f);
        k1.w = __expf(20.f * acc[i][7] - 20.f);
        *reinterpret_cast<float4*>(&Km[(size_t)row * B + c0 + tx * 4]) = k0;
        *reinterpret_cast<float4*>(&Km[(size_t)row * B + c0 + 64 + tx * 4]) = k1;
    }
}

// ---------------------------------------------------------------------------
// Relaxed agent-scope atomic helpers: bypass the non-coherent L1/L2 and hit
// the coherent LLC directly, WITHOUT the buffer_inv / buffer_wbl2 cache-
// maintenance ops that acquire/release emit (round-3 post-mortem: those ops,
// issued per poll iteration chip-wide, were ~83 us/barrier).
// ---------------------------------------------------------------------------
__device__ __forceinline__ unsigned ld_rlx(const unsigned* p) {
    return __hip_atomic_load(p, __ATOMIC_RELAXED, __HIP_MEMORY_SCOPE_AGENT);
}
__device__ __forceinline__ void st_rlx(unsigned* p, unsigned v) {
    __hip_atomic_store(p, v, __ATOMIC_RELAXED, __HIP_MEMORY_SCOPE_AGENT);
}
__device__ __forceinline__ float ldf_rlx(const float* p) {
    return __hip_atomic_load(p, __ATOMIC_RELAXED, __HIP_MEMORY_SCOPE_AGENT);
}
__device__ __forceinline__ void stf_rlx(float* p, float v) {
    __hip_atomic_store(p, v, __ATOMIC_RELAXED, __HIP_MEMORY_SCOPE_AGENT);
}

// Grid barrier, all-relaxed. Producer ordering: data stores are drained by
// the s_waitcnt vmcnt(0) that __syncthreads performs; an explicit waitcnt
// before each flag store is belt-and-braces (same wave issues data + flag).
// Consumer ordering: control dependency + in-order VMEM issue after the
// observed poll; data reads are themselves LLC-direct relaxed atomics.
__device__ __forceinline__ void gridbar(unsigned* flags, unsigned* go,
                                        int bid, int t0, unsigned phase) {
    __syncthreads();
    if (t0 == 0) {
        asm volatile("s_waitcnt vmcnt(0)" ::: "memory");
        st_rlx(&flags[bid], phase);
    }
    if (bid == 0) {
        if (t0 < NBLK) {
            while (ld_rlx(&flags[t0]) < phase)
                __builtin_amdgcn_s_sleep(1);
        }
        __syncthreads();
        if (t0 == 0) {
            asm volatile("s_waitcnt vmcnt(0)" ::: "memory");
            st_rlx(go, phase);
        }
    }
    if (t0 == 0) {
        while (ld_rlx(go) < phase)
            __builtin_amdgcn_s_sleep(1);
    }
    __syncthreads();
}

// ---------------------------------------------------------------------------
// Kernel 3 v3: persistent Sinkhorn + loss. Zero atomicAdds in the loop, zero
// cache-maintenance ops. Block owns 8 rows (kr) and 8 cols (kc), K register-
// resident for all 20 iterations; cross-block words (s, a_glob, flags) only
// ever touched via relaxed agent atomics.
// ---------------------------------------------------------------------------
__global__ __launch_bounds__(1024) void sink_k(const float* __restrict__ Km,
                                               float* __restrict__ s,
                                               float* __restrict__ a_glob,
                                               unsigned* __restrict__ flags,
                                               float* __restrict__ out) {
    __shared__ float part[8][16];
    __shared__ float a8[8];
    int t0 = threadIdx.x;
    int lane = t0 & 63, wv = t0 >> 6;
    int bid = blockIdx.x;
    int r0 = bid * 8;          // owned rows
    int c0 = bid * 8;          // owned cols
    int jx = 2 * t0;           // this thread's 2 columns (row phase)
    unsigned* go = flags + NBLK;

    // preload row block: K[r0+i][jx..jx+1]  (coalesced)
    float2 kr[8];
    #pragma unroll
    for (int i = 0; i < 8; ++i)
        kr[i] = *reinterpret_cast<const float2*>(&Km[(size_t)(r0 + i) * B + jx]);

    // preload col block: rows {2*t0, 2*t0+1} x cols c0..c0+7 (gathered, L3-hot)
    float4 kc[4];
    {
        const float4* p0 = reinterpret_cast<const float4*>(&Km[(size_t)(2 * t0) * B + c0]);
        const float4* p1 = reinterpret_cast<const float4*>(&Km[(size_t)(2 * t0 + 1) * B + c0]);
        kc[0] = p0[0]; kc[1] = p0[1];
        kc[2] = p1[0]; kc[3] = p1[1];
    }

    for (int t = 1; t <= 20; ++t) {
        // ---- row phase: a = 1/(K * (1/s)) ----
        float bx = 1.0f, by = 1.0f;
        if (t > 1) {
            bx = 1.0f / ldf_rlx(&s[jx]);
            by = 1.0f / ldf_rlx(&s[jx + 1]);
        }
        #pragma unroll
        for (int i = 0; i < 8; ++i) {
            float v = fmaf(kr[i].x, bx, kr[i].y * by);
            #pragma unroll
            for (int m = 32; m >= 1; m >>= 1) v += __shfl_xor(v, m, 64);
            if (lane == 0) part[i][wv] = v;
        }
        __syncthreads();
        if (t0 < 8) {
            float sum = 0.f;
            #pragma unroll
            for (int w = 0; w < 16; ++w) sum += part[t0][w];
            float av = 1.0f / sum;
            a8[t0] = av;
            stf_rlx(&a_glob[r0 + t0], av);
        }
        gridbar(flags, go, bid, t0, (unsigned)(2 * t - 1));

        // ---- col phase: s[c] = sum_i a_i K[i][c]  (owned columns) ----
        float av0 = ldf_rlx(&a_glob[2 * t0]);
        float av1 = ldf_rlx(&a_glob[2 * t0 + 1]);
        float p[8];
        #pragma unroll
        for (int c = 0; c < 4; ++c) {
            p[c]     = fmaf(av0, kc[0][c], av1 * kc[2][c]);
            p[4 + c] = fmaf(av0, kc[1][c], av1 * kc[3][c]);
        }
        #pragma unroll
        for (int c = 0; c < 8; ++c) {
            float v = p[c];
            #pragma unroll
            for (int m = 32; m >= 1; m >>= 1) v += __shfl_xor(v, m, 64);
            if (lane == 0) part[c][wv] = v;
        }
        __syncthreads();
        if (t0 < 8) {
            float sum = 0.f;
            #pragma unroll
            for (int w = 0; w < 16; ++w) sum += part[t0][w];
            stf_rlx(&s[c0 + t0], sum);
        }
        gridbar(flags, go, bid, t0, (unsigned)(2 * t));
    }

    // ---- fused loss: -1e-4 * sum_ij a_i K_ij (1/s20_j) ln K_ij ----
    float bx = 1.0f / ldf_rlx(&s[jx]);
    float by = 1.0f / ldf_rlx(&s[jx + 1]);
    float acc = 0.f;
    #pragma unroll
    for (int i = 0; i < 8; ++i) {
        float ai = a8[i];   // this block's own rows' a from iteration 20
        acc += ai * (kr[i].x * bx * __logf(kr[i].x) +
                     kr[i].y * by * __logf(kr[i].y));
    }
    #pragma unroll
    for (int m = 32; m >= 1; m >>= 1) acc += __shfl_xor(acc, m, 64);
    if (lane == 0) part[0][wv] = acc;
    __syncthreads();
    if (t0 == 0) {
        float sum = 0.f;
        #pragma unroll
        for (int w = 0; w < 16; ++w) sum += part[0][w];
        atomicAdd(out, -0.1f * 0.001f * sum);
    }
}

// ---------------------------------------------------------------------------
extern "C" void kernel_launch(void* const* d_in, const int* in_sizes, int n_in,
                              void* d_out, int out_size, void* d_ws, size_t ws_size,
                              hipStream_t stream) {
    const float* ys = (const float*)d_in[0];
    const float* yt = (const float*)d_in[1];
    float* out = (float*)d_out;

    char* wsb = (char*)d_ws;
    _Float16* ps = (_Float16*)wsb;                               // 4 MB
    _Float16* pt = (_Float16*)(wsb + (size_t)B * C * 2);         // 4 MB
    float* Km    = (float*)(wsb + (size_t)2 * B * C * 2);        // 16.8 MB
    float* s     = Km + (size_t)B * B;                           // B floats
    float* a_glob = s + B;                                       // B floats
    unsigned* flags = (unsigned*)(a_glob + B);                   // NBLK + 1

    (void)hipMemsetAsync(flags, 0, (NBLK + 1) * sizeof(unsigned), stream);
    (void)hipMemsetAsync(out, 0, sizeof(float), stream);

    softmax_k<<<2 * B, 256, 0, stream>>>(ys, yt, ps, pt);
    cdist_k<<<dim3(16, 16), 512, 0, stream>>>(ps, pt, Km);
    sink_k<<<NBLK, 1024, 0, stream>>>(Km, s, a_glob, flags, out);
}

// Round 5
// 413.857 us; speedup vs baseline: 8.4227x; 1.0800x over previous
//
#include <hip/hip_runtime.h>
#include <math.h>

#define B 2048
#define C 1024
#define NBLK 256   // persistent grid == CU count; 1 block/CU guarantees co-residency

typedef _Float16 v2h __attribute__((ext_vector_type(2)));

// ---------------------------------------------------------------------------
// Kernel 1: row softmax of y/2 for both inputs -> fp16 output. (unchanged)
// ---------------------------------------------------------------------------
__global__ __launch_bounds__(256) void softmax_k(const float* __restrict__ ys,
                                                 const float* __restrict__ yt,
                                                 _Float16* __restrict__ ps,
                                                 _Float16* __restrict__ pt) {
    int b = blockIdx.x;
    const float* in;
    _Float16* out;
    if (b < B) { in = ys + (size_t)b * C;        out = ps + (size_t)b * C; }
    else       { in = yt + (size_t)(b - B) * C;  out = pt + (size_t)(b - B) * C; }
    int tid = threadIdx.x;
    int lane = tid & 63, wave = tid >> 6;

    float4 v = reinterpret_cast<const float4*>(in)[tid];
    v.x *= 0.5f; v.y *= 0.5f; v.z *= 0.5f; v.w *= 0.5f;

    float mx = fmaxf(fmaxf(v.x, v.y), fmaxf(v.z, v.w));
    #pragma unroll
    for (int m = 32; m >= 1; m >>= 1) mx = fmaxf(mx, __shfl_xor(mx, m, 64));
    __shared__ float redm[4];
    if (lane == 0) redm[wave] = mx;
    __syncthreads();
    mx = fmaxf(fmaxf(redm[0], redm[1]), fmaxf(redm[2], redm[3]));

    float4 e;
    e.x = expf(v.x - mx); e.y = expf(v.y - mx);
    e.z = expf(v.z - mx); e.w = expf(v.w - mx);
    float s = e.x + e.y + e.z + e.w;
    #pragma unroll
    for (int m = 32; m >= 1; m >>= 1) s += __shfl_xor(s, m, 64);
    __shared__ float reds[4];
    if (lane == 0) reds[wave] = s;
    __syncthreads();
    s = reds[0] + reds[1] + reds[2] + reds[3];

    float inv = 1.0f / s;
    float2 st;
    v2h* sp = (v2h*)&st;
    sp[0] = (v2h){(_Float16)(e.x * inv), (_Float16)(e.y * inv)};
    sp[1] = (v2h){(_Float16)(e.z * inv), (_Float16)(e.w * inv)};
    reinterpret_cast<float2*>(out)[tid] = st;
}

// ---------------------------------------------------------------------------
// Kernel 2 v4: K[i][j] = exp(20*S - 20), S = sum_c min(ps[i,c], pt[j,c]).
// 1024 threads (4 waves/SIMD -> hide LDS/latency bubbles), 128x128 tile,
// 2x8 frags. Chunk depth 64, fp16 fold every 16 k2 (chain length identical
// to v3 -> bitwise-identical S). launch_bounds(1024,4) caps VGPR at 128.
// ---------------------------------------------------------------------------
__global__ __launch_bounds__(1024, 4) void cdist_k(const _Float16* __restrict__ ps,
                                                   const _Float16* __restrict__ pt,
                                                   float* __restrict__ Km) {
    __shared__ __align__(16) v2h As[32][132];
    __shared__ __align__(16) v2h Bs[32][132];
    int tid = threadIdx.x;
    int tx = tid & 15;          // col group: c0+tx*4..+3 and c0+64+tx*4..+3
    int ty = tid >> 4;          // [0,64): rows {2ty, 2ty+1}
    int r0 = blockIdx.y * 128, c0 = blockIdx.x * 128;

    float acc[2][8];
    v2h csum[2][8];
    #pragma unroll
    for (int i = 0; i < 2; ++i)
        #pragma unroll
        for (int j = 0; j < 8; ++j) {
            acc[i][j] = 0.f;
            csum[i][j] = (v2h){(_Float16)0.f, (_Float16)0.f};
        }

    int lr = tid >> 3;          // [0,128): staging row
    int lq = tid & 7;           // float4 slot within the 128B chunk
    const float4* pa = reinterpret_cast<const float4*>(ps + (size_t)(r0 + lr) * C);
    const float4* pb = reinterpret_cast<const float4*>(pt + (size_t)(c0 + lr) * C);
    const v2h one2 = {(_Float16)1.0f, (_Float16)1.0f};

    // prefetch ch=0
    float4 a0 = pa[lq];
    float4 b0 = pb[lq];

    for (int ch = 0; ch < 16; ++ch) {
        v2h* ah = (v2h*)&a0;
        v2h* bh = (v2h*)&b0;
        #pragma unroll
        for (int c2 = 0; c2 < 4; ++c2) {
            As[lq * 4 + c2][lr] = ah[c2];
            Bs[lq * 4 + c2][lr] = bh[c2];
        }
        __syncthreads();

        // issue next chunk's loads; latency hides under the k2 compute
        int nch = (ch + 1) & 15;
        float4 na = pa[nch * 8 + lq];
        float4 nb = pb[nch * 8 + lq];

        #pragma unroll
        for (int half = 0; half < 2; ++half) {
            #pragma unroll
            for (int k2 = 0; k2 < 16; ++k2) {
                int kk = half * 16 + k2;
                v2h a2[2], b2[8];
                *(float2*)&a2[0] = *(const float2*)&As[kk][ty * 2];
                *(float4*)&b2[0] = *(const float4*)&Bs[kk][tx * 4];
                *(float4*)&b2[4] = *(const float4*)&Bs[kk][64 + tx * 4];
                #pragma unroll
                for (int i = 0; i < 2; ++i)
                    #pragma unroll
                    for (int j = 0; j < 8; ++j)
                        csum[i][j] += __builtin_elementwise_min(a2[i], b2[j]);
            }
            // fold 16-term fp16 chunk sums into f32 accumulators
            #pragma unroll
            for (int i = 0; i < 2; ++i)
                #pragma unroll
                for (int j = 0; j < 8; ++j) {
#if __has_builtin(__builtin_amdgcn_fdot2)
                    acc[i][j] = __builtin_amdgcn_fdot2(csum[i][j], one2, acc[i][j], false);
#else
                    acc[i][j] += (float)csum[i][j].x + (float)csum[i][j].y;
#endif
                    csum[i][j] = (v2h){(_Float16)0.f, (_Float16)0.f};
                }
        }
        __syncthreads();
        a0 = na; b0 = nb;
    }

    #pragma unroll
    for (int i = 0; i < 2; ++i) {
        int row = r0 + ty * 2 + i;
        float4 k0, k1;
        k0.x = __expf(20.f * acc[i][0] - 20.f);
        k0.y = __expf(20.f * acc[i][1] - 20.f);
        k0.z = __expf(20.f * acc[i][2] - 20.f);
        k0.w = __expf(20.f * acc[i][3] - 20.f);
        k1.x = __expf(20.f * acc[i][4] - 20.f);
        k1.y = __expf(20.f * acc[i][5] - 20.f);
        k1.z = __expf(20.f * acc[i][6] - 20.f);
        k1.w = __expf(20.f * acc[i][7] - 20.f);
        *reinterpret_cast<float4*>(&Km[(size_t)row * B + c0 + tx * 4]) = k0;
        *reinterpret_cast<float4*>(&Km[(size_t)row * B + c0 + 64 + tx * 4]) = k1;
    }
}

// ---------------------------------------------------------------------------
// Relaxed agent-scope atomics: LLC-direct, no cache-maintenance ops
// (validated round 4: coherent cross-XCD, ~0 overhead).
// ---------------------------------------------------------------------------
__device__ __forceinline__ void stf_rlx(float* p, float v) {
    __hip_atomic_store(p, v, __ATOMIC_RELAXED, __HIP_MEMORY_SCOPE_AGENT);
}

// Dataflow sync: versioned buffers are pre-set to the 0xFFFFFFFF sentinel
// (negative NaN -- unreachable: all produced values are positive). Consumer
// spins on the 8B pair it needs; the data IS the flag. One LLC round trip
// per dependency, no global barrier, fast blocks pipeline ahead.
__device__ __forceinline__ float2 poll2(const float* p) {
    const unsigned long long* q = reinterpret_cast<const unsigned long long*>(p);
    unsigned long long v = __hip_atomic_load(q, __ATOMIC_RELAXED,
                                             __HIP_MEMORY_SCOPE_AGENT);
    while ((unsigned)v == 0xFFFFFFFFu || (unsigned)(v >> 32) == 0xFFFFFFFFu) {
        __builtin_amdgcn_s_sleep(1);
        v = __hip_atomic_load(q, __ATOMIC_RELAXED, __HIP_MEMORY_SCOPE_AGENT);
    }
    float2 r;
    r.x = __uint_as_float((unsigned)v);
    r.y = __uint_as_float((unsigned)(v >> 32));
    return r;
}

// ---------------------------------------------------------------------------
// Kernel 3 v4: persistent Sinkhorn + loss, ZERO grid barriers. Block owns 8
// rows (kr) and 8 cols (kc), K register-resident; s_t and a_t are versioned
// per iteration and consumed via sentinel-poll dataflow sync.
// ---------------------------------------------------------------------------
__global__ __launch_bounds__(1024) void sink_k(const float* __restrict__ Km,
                                               float* __restrict__ sbuf,
                                               float* __restrict__ abuf,
                                               float* __restrict__ out) {
    __shared__ float part[8][16];
    __shared__ float a8[8];
    int t0 = threadIdx.x;
    int lane = t0 & 63, wv = t0 >> 6;
    int bid = blockIdx.x;
    int r0 = bid * 8;          // owned rows
    int c0 = bid * 8;          // owned cols
    int jx = 2 * t0;           // this thread's 2 columns (row phase)

    // preload row block: K[r0+i][jx..jx+1]  (coalesced)
    float2 kr[8];
    #pragma unroll
    for (int i = 0; i < 8; ++i)
        kr[i] = *reinterpret_cast<const float2*>(&Km[(size_t)(r0 + i) * B + jx]);

    // preload col block: rows {2*t0, 2*t0+1} x cols c0..c0+7 (gathered)
    float4 kc[4];
    {
        const float4* p0 = reinterpret_cast<const float4*>(&Km[(size_t)(2 * t0) * B + c0]);
        const float4* p1 = reinterpret_cast<const float4*>(&Km[(size_t)(2 * t0 + 1) * B + c0]);
        kc[0] = p0[0]; kc[1] = p0[1];
        kc[2] = p1[0]; kc[3] = p1[1];
    }

    for (int t = 1; t <= 20; ++t) {
        // ---- row phase: a = 1/(K * (1/s_{t-1})) ----
        float bx = 1.0f, by = 1.0f;
        if (t > 1) {
            float2 sv = poll2(&sbuf[(size_t)(t - 2) * B + jx]);
            bx = 1.0f / sv.x; by = 1.0f / sv.y;
        }
        #pragma unroll
        for (int i = 0; i < 8; ++i) {
            float v = fmaf(kr[i].x, bx, kr[i].y * by);
            #pragma unroll
            for (int m = 32; m >= 1; m >>= 1) v += __shfl_xor(v, m, 64);
            if (lane == 0) part[i][wv] = v;
        }
        __syncthreads();
        float* a_t = abuf + (size_t)(t - 1) * B;
        if (t0 < 8) {
            float sum = 0.f;
            #pragma unroll
            for (int w = 0; w < 16; ++w) sum += part[t0][w];
            float av = 1.0f / sum;
            a8[t0] = av;
            stf_rlx(&a_t[r0 + t0], av);
        }
        __syncthreads();   // part[] reads done before col phase rewrites it

        // ---- col phase: s_t[c] = sum_i a_i K[i][c]  (owned columns) ----
        float2 av2 = poll2(&a_t[2 * t0]);
        float p[8];
        #pragma unroll
        for (int c = 0; c < 4; ++c) {
            p[c]     = fmaf(av2.x, kc[0][c], av2.y * kc[2][c]);
            p[4 + c] = fmaf(av2.x, kc[1][c], av2.y * kc[3][c]);
        }
        #pragma unroll
        for (int c = 0; c < 8; ++c) {
            float v = p[c];
            #pragma unroll
            for (int m = 32; m >= 1; m >>= 1) v += __shfl_xor(v, m, 64);
            if (lane == 0) part[c][wv] = v;
        }
        __syncthreads();
        float* s_t = sbuf + (size_t)(t - 1) * B;
        if (t0 < 8) {
            float sum = 0.f;
            #pragma unroll
            for (int w = 0; w < 16; ++w) sum += part[t0][w];
            stf_rlx(&s_t[c0 + t0], sum);
        }
        __syncthreads();   // part[] reads done before next phase rewrites it
    }

    // ---- fused loss: -1e-4 * sum_ij a_i K_ij (1/s20_j) ln K_ij ----
    float2 sv = poll2(&sbuf[(size_t)19 * B + jx]);
    float bx = 1.0f / sv.x, by = 1.0f / sv.y;
    float acc = 0.f;
    #pragma unroll
    for (int i = 0; i < 8; ++i) {
        float ai = a8[i];   // this block's own rows' a from iteration 20
        acc += ai * (kr[i].x * bx * __logf(kr[i].x) +
                     kr[i].y * by * __logf(kr[i].y));
    }
    #pragma unroll
    for (int m = 32; m >= 1; m >>= 1) acc += __shfl_xor(acc, m, 64);
    if (lane == 0) part[0][wv] = acc;
    __syncthreads();
    if (t0 == 0) {
        float sum = 0.f;
        #pragma unroll
        for (int w = 0; w < 16; ++w) sum += part[0][w];
        atomicAdd(out, -0.1f * 0.001f * sum);
    }
}

// ---------------------------------------------------------------------------
extern "C" void kernel_launch(void* const* d_in, const int* in_sizes, int n_in,
                              void* d_out, int out_size, void* d_ws, size_t ws_size,
                              hipStream_t stream) {
    const float* ys = (const float*)d_in[0];
    const float* yt = (const float*)d_in[1];
    float* out = (float*)d_out;

    char* wsb = (char*)d_ws;
    _Float16* ps = (_Float16*)wsb;                               // 4 MB
    _Float16* pt = (_Float16*)(wsb + (size_t)B * C * 2);         // 4 MB
    float* Km    = (float*)(wsb + (size_t)2 * B * C * 2);        // 16.8 MB
    float* sbuf  = Km + (size_t)B * B;                           // 20*B floats
    float* abuf  = sbuf + (size_t)20 * B;                        // 20*B floats

    // sentinel-fill both versioned buffers (0xFF bytes -> negative NaN)
    (void)hipMemsetAsync(sbuf, 0xFF, (size_t)40 * B * sizeof(float), stream);
    (void)hipMemsetAsync(out, 0, sizeof(float), stream);

    softmax_k<<<2 * B, 256, 0, stream>>>(ys, yt, ps, pt);
    cdist_k<<<dim3(16, 16), 1024, 0, stream>>>(ps, pt, Km);
    sink_k<<<NBLK, 1024, 0, stream>>>(Km, sbuf, abuf, out);
}

// Round 6
// 373.086 us; speedup vs baseline: 9.3431x; 1.1093x over previous
//
#include <hip/hip_runtime.h>
#include <math.h>

#define B 2048
#define C 1024
#define NBLK 256   // persistent grid == CU count; 1 block/CU guarantees co-residency

typedef _Float16 v2h __attribute__((ext_vector_type(2)));

// ---------------------------------------------------------------------------
// Kernel 1: row softmax of y/2 for both inputs -> fp16 output. (unchanged)
// ---------------------------------------------------------------------------
__global__ __launch_bounds__(256) void softmax_k(const float* __restrict__ ys,
                                                 const float* __restrict__ yt,
                                                 _Float16* __restrict__ ps,
                                                 _Float16* __restrict__ pt) {
    int b = blockIdx.x;
    const float* in;
    _Float16* out;
    if (b < B) { in = ys + (size_t)b * C;        out = ps + (size_t)b * C; }
    else       { in = yt + (size_t)(b - B) * C;  out = pt + (size_t)(b - B) * C; }
    int tid = threadIdx.x;
    int lane = tid & 63, wave = tid >> 6;

    float4 v = reinterpret_cast<const float4*>(in)[tid];
    v.x *= 0.5f; v.y *= 0.5f; v.z *= 0.5f; v.w *= 0.5f;

    float mx = fmaxf(fmaxf(v.x, v.y), fmaxf(v.z, v.w));
    #pragma unroll
    for (int m = 32; m >= 1; m >>= 1) mx = fmaxf(mx, __shfl_xor(mx, m, 64));
    __shared__ float redm[4];
    if (lane == 0) redm[wave] = mx;
    __syncthreads();
    mx = fmaxf(fmaxf(redm[0], redm[1]), fmaxf(redm[2], redm[3]));

    float4 e;
    e.x = expf(v.x - mx); e.y = expf(v.y - mx);
    e.z = expf(v.z - mx); e.w = expf(v.w - mx);
    float s = e.x + e.y + e.z + e.w;
    #pragma unroll
    for (int m = 32; m >= 1; m >>= 1) s += __shfl_xor(s, m, 64);
    __shared__ float reds[4];
    if (lane == 0) reds[wave] = s;
    __syncthreads();
    s = reds[0] + reds[1] + reds[2] + reds[3];

    float inv = 1.0f / s;
    float2 st;
    v2h* sp = (v2h*)&st;
    sp[0] = (v2h){(_Float16)(e.x * inv), (_Float16)(e.y * inv)};
    sp[1] = (v2h){(_Float16)(e.z * inv), (_Float16)(e.w * inv)};
    reinterpret_cast<float2*>(out)[tid] = st;
}

// ---------------------------------------------------------------------------
// Kernel 2 v5: structure identical to v4 (1024 thr, 128x128 tile, 2x8 frags,
// fold every 16 k2 -> bitwise-identical S). Two changes, one theory:
//   * amdgpu_waves_per_eu(4,4): truthfully forces 4 waves/EU (16-wave block,
//     grid=256 -> 1 block/CU), giving the allocator the full 128-VGPR/wave
//     budget instead of its self-chosen 40.
//   * inner pk_min/pk_add and the dot2 fold pinned to arch VGPRs via inline
//     asm "v" constraints -- round-5 counters showed 5.5 cyc/VALU-instr
//     (2.75x bloat), the accvgpr-wrap / scalarization signature.
// ---------------------------------------------------------------------------
__global__ __launch_bounds__(1024)
__attribute__((amdgpu_waves_per_eu(4, 4)))
void cdist_k(const _Float16* __restrict__ ps,
             const _Float16* __restrict__ pt,
             float* __restrict__ Km) {
    __shared__ __align__(16) v2h As[32][132];
    __shared__ __align__(16) v2h Bs[32][132];
    int tid = threadIdx.x;
    int tx = tid & 15;          // col group: c0+tx*4..+3 and c0+64+tx*4..+3
    int ty = tid >> 4;          // [0,64): rows {2ty, 2ty+1}
    int r0 = blockIdx.y * 128, c0 = blockIdx.x * 128;

    float acc[2][8];
    v2h csum[2][8];
    #pragma unroll
    for (int i = 0; i < 2; ++i)
        #pragma unroll
        for (int j = 0; j < 8; ++j) {
            acc[i][j] = 0.f;
            csum[i][j] = (v2h){(_Float16)0.f, (_Float16)0.f};
        }

    int lr = tid >> 3;          // [0,128): staging row
    int lq = tid & 7;           // float4 slot within the 128B chunk
    const float4* pa = reinterpret_cast<const float4*>(ps + (size_t)(r0 + lr) * C);
    const float4* pb = reinterpret_cast<const float4*>(pt + (size_t)(c0 + lr) * C);
    const v2h one2 = {(_Float16)1.0f, (_Float16)1.0f};

    // prefetch ch=0
    float4 a0 = pa[lq];
    float4 b0 = pb[lq];

    for (int ch = 0; ch < 16; ++ch) {
        v2h* ah = (v2h*)&a0;
        v2h* bh = (v2h*)&b0;
        #pragma unroll
        for (int c2 = 0; c2 < 4; ++c2) {
            As[lq * 4 + c2][lr] = ah[c2];
            Bs[lq * 4 + c2][lr] = bh[c2];
        }
        __syncthreads();

        // issue next chunk's loads; latency hides under the k2 compute
        int nch = (ch + 1) & 15;
        float4 na = pa[nch * 8 + lq];
        float4 nb = pb[nch * 8 + lq];

        #pragma unroll
        for (int half = 0; half < 2; ++half) {
            #pragma unroll
            for (int k2 = 0; k2 < 16; ++k2) {
                int kk = half * 16 + k2;
                v2h a2[2], b2[8];
                *(float2*)&a2[0] = *(const float2*)&As[kk][ty * 2];
                *(float4*)&b2[0] = *(const float4*)&Bs[kk][tx * 4];
                *(float4*)&b2[4] = *(const float4*)&Bs[kk][64 + tx * 4];
                #pragma unroll
                for (int i = 0; i < 2; ++i)
                    #pragma unroll
                    for (int j = 0; j < 8; ++j) {
                        v2h mn;
                        asm("v_pk_min_f16 %0, %1, %2"
                            : "=v"(mn) : "v"(a2[i]), "v"(b2[j]));
                        asm("v_pk_add_f16 %0, %0, %1"
                            : "+v"(csum[i][j]) : "v"(mn));
                    }
            }
            // fold 16-term fp16 chunk sums into f32 accumulators
            #pragma unroll
            for (int i = 0; i < 2; ++i)
                #pragma unroll
                for (int j = 0; j < 8; ++j) {
                    asm("v_dot2_f32_f16 %0, %1, %2, %0"
                        : "+v"(acc[i][j]) : "v"(csum[i][j]), "v"(one2));
                    csum[i][j] = (v2h){(_Float16)0.f, (_Float16)0.f};
                }
        }
        __syncthreads();
        a0 = na; b0 = nb;
    }

    #pragma unroll
    for (int i = 0; i < 2; ++i) {
        int row = r0 + ty * 2 + i;
        float4 k0, k1;
        k0.x = __expf(20.f * acc[i][0] - 20.f);
        k0.y = __expf(20.f * acc[i][1] - 20.f);
        k0.z = __expf(20.f * acc[i][2] - 20.f);
        k0.w = __expf(20.f * acc[i][3] - 20.f);
        k1.x = __expf(20.f * acc[i][4] - 20.f);
        k1.y = __expf(20.f * acc[i][5] - 20.f);
        k1.z = __expf(20.f * acc[i][6] - 20.f);
        k1.w = __expf(20.f * acc[i][7] - 20.f);
        *reinterpret_cast<float4*>(&Km[(size_t)row * B + c0 + tx * 4]) = k0;
        *reinterpret_cast<float4*>(&Km[(size_t)row * B + c0 + 64 + tx * 4]) = k1;
    }
}

// ---------------------------------------------------------------------------
// Relaxed agent-scope atomics: LLC-direct, no cache-maintenance ops
// (validated round 4: coherent cross-XCD, ~0 overhead).
// ---------------------------------------------------------------------------
__device__ __forceinline__ void stf_rlx(float* p, float v) {
    __hip_atomic_store(p, v, __ATOMIC_RELAXED, __HIP_MEMORY_SCOPE_AGENT);
}
__device__ __forceinline__ float2 poll2(const float* p) {
    const unsigned long long* q = reinterpret_cast<const unsigned long long*>(p);
    unsigned long long v = __hip_atomic_load(q, __ATOMIC_RELAXED,
                                             __HIP_MEMORY_SCOPE_AGENT);
    while ((unsigned)v == 0xFFFFFFFFu || (unsigned)(v >> 32) == 0xFFFFFFFFu) {
        __builtin_amdgcn_s_sleep(1);
        v = __hip_atomic_load(q, __ATOMIC_RELAXED, __HIP_MEMORY_SCOPE_AGENT);
    }
    float2 r;
    r.x = __uint_as_float((unsigned)v);
    r.y = __uint_as_float((unsigned)(v >> 32));
    return r;
}
__device__ __forceinline__ float4 poll4(const float* p) {
    float2 lo = poll2(p);
    float2 hi = poll2(p + 2);
    return make_float4(lo.x, lo.y, hi.x, hi.y);
}

// ---------------------------------------------------------------------------
// Kernel 3 v5: persistent Sinkhorn + loss, dataflow-sync'd (validated r4/r5).
// Leaner phases: 512 threads (8 waves, not 16). Thread owns 4 COLS of the
// block's 8 rows (kr, row phase) and 4 ROWS x 8 owned cols (kc, col phase).
// Halves total shuffle count and syncthreads width vs v4's 1024 threads.
// ---------------------------------------------------------------------------
__global__ __launch_bounds__(512) void sink_k(const float* __restrict__ Km,
                                              float* __restrict__ sbuf,
                                              float* __restrict__ abuf,
                                              float* __restrict__ out) {
    __shared__ float part[8][8];
    __shared__ float a8[8];
    int t0 = threadIdx.x;
    int lane = t0 & 63, wv = t0 >> 6;      // 8 waves
    int bid = blockIdx.x;
    int r0 = bid * 8;          // owned rows
    int c0 = bid * 8;          // owned cols
    int jx = 4 * t0;           // this thread's 4 columns (row phase)
    int rr = 4 * t0;           // this thread's 4 rows (col phase)

    // row block: K[r0+i][jx..jx+3]  (coalesced float4 per row)
    float4 kr[8];
    #pragma unroll
    for (int i = 0; i < 8; ++i)
        kr[i] = *reinterpret_cast<const float4*>(&Km[(size_t)(r0 + i) * B + jx]);

    // col block: rows rr..rr+3 x cols c0..c0+7 (gathered once, 8x float4)
    float4 kclo[4], kchi[4];
    #pragma unroll
    for (int i = 0; i < 4; ++i) {
        kclo[i] = *reinterpret_cast<const float4*>(&Km[(size_t)(rr + i) * B + c0]);
        kchi[i] = *reinterpret_cast<const float4*>(&Km[(size_t)(rr + i) * B + c0 + 4]);
    }

    for (int t = 1; t <= 20; ++t) {
        // ---- row phase: a = 1/(K * (1/s_{t-1})) ----
        float4 binv = make_float4(1.f, 1.f, 1.f, 1.f);
        if (t > 1) {
            float4 sv = poll4(&sbuf[(size_t)(t - 2) * B + jx]);
            binv.x = 1.0f / sv.x; binv.y = 1.0f / sv.y;
            binv.z = 1.0f / sv.z; binv.w = 1.0f / sv.w;
        }
        #pragma unroll
        for (int i = 0; i < 8; ++i) {
            float v = kr[i].x * binv.x + kr[i].y * binv.y
                    + kr[i].z * binv.z + kr[i].w * binv.w;
            #pragma unroll
            for (int m = 32; m >= 1; m >>= 1) v += __shfl_xor(v, m, 64);
            if (lane == 0) part[i][wv] = v;
        }
        __syncthreads();
        float* a_t = abuf + (size_t)(t - 1) * B;
        if (t0 < 8) {
            float sum = 0.f;
            #pragma unroll
            for (int w = 0; w < 8; ++w) sum += part[t0][w];
            float av = 1.0f / sum;
            a8[t0] = av;
            stf_rlx(&a_t[r0 + t0], av);
        }
        __syncthreads();   // part[] consumed before col phase rewrites it

        // ---- col phase: s_t[c] = sum_i a_i K[i][c]  (owned columns) ----
        float4 av4 = poll4(&a_t[rr]);   // a for this thread's 4 rows
        float p[8];
        #pragma unroll
        for (int c = 0; c < 4; ++c) {
            p[c]     = av4.x * kclo[0][c] + av4.y * kclo[1][c]
                     + av4.z * kclo[2][c] + av4.w * kclo[3][c];
            p[4 + c] = av4.x * kchi[0][c] + av4.y * kchi[1][c]
                     + av4.z * kchi[2][c] + av4.w * kchi[3][c];
        }
        #pragma unroll
        for (int c = 0; c < 8; ++c) {
            float v = p[c];
            #pragma unroll
            for (int m = 32; m >= 1; m >>= 1) v += __shfl_xor(v, m, 64);
            if (lane == 0) part[c][wv] = v;
        }
        __syncthreads();
        float* s_t = sbuf + (size_t)(t - 1) * B;
        if (t0 < 8) {
            float sum = 0.f;
            #pragma unroll
            for (int w = 0; w < 8; ++w) sum += part[t0][w];
            stf_rlx(&s_t[c0 + t0], sum);
        }
        __syncthreads();   // part[] consumed before next phase rewrites it
    }

    // ---- fused loss: -1e-4 * sum_ij a_i K_ij (1/s20_j) ln K_ij ----
    float4 sv = poll4(&sbuf[(size_t)19 * B + jx]);
    float4 binv;
    binv.x = 1.0f / sv.x; binv.y = 1.0f / sv.y;
    binv.z = 1.0f / sv.z; binv.w = 1.0f / sv.w;
    float acc = 0.f;
    #pragma unroll
    for (int i = 0; i < 8; ++i) {
        float ai = a8[i];   // this block's own rows' a from iteration 20
        acc += ai * (kr[i].x * binv.x * __logf(kr[i].x) +
                     kr[i].y * binv.y * __logf(kr[i].y) +
                     kr[i].z * binv.z * __logf(kr[i].z) +
                     kr[i].w * binv.w * __logf(kr[i].w));
    }
    #pragma unroll
    for (int m = 32; m >= 1; m >>= 1) acc += __shfl_xor(acc, m, 64);
    if (lane == 0) part[0][wv] = acc;
    __syncthreads();
    if (t0 == 0) {
        float sum = 0.f;
        #pragma unroll
        for (int w = 0; w < 8; ++w) sum += part[0][w];
        atomicAdd(out, -0.1f * 0.001f * sum);
    }
}

// ---------------------------------------------------------------------------
extern "C" void kernel_launch(void* const* d_in, const int* in_sizes, int n_in,
                              void* d_out, int out_size, void* d_ws, size_t ws_size,
                              hipStream_t stream) {
    const float* ys = (const float*)d_in[0];
    const float* yt = (const float*)d_in[1];
    float* out = (float*)d_out;

    char* wsb = (char*)d_ws;
    _Float16* ps = (_Float16*)wsb;                               // 4 MB
    _Float16* pt = (_Float16*)(wsb + (size_t)B * C * 2);         // 4 MB
    float* Km    = (float*)(wsb + (size_t)2 * B * C * 2);        // 16.8 MB
    float* sbuf  = Km + (size_t)B * B;                           // 20*B floats
    float* abuf  = sbuf + (size_t)20 * B;                        // 20*B floats

    // sentinel-fill both versioned buffers (0xFF bytes -> negative NaN)
    (void)hipMemsetAsync(sbuf, 0xFF, (size_t)40 * B * sizeof(float), stream);
    (void)hipMemsetAsync(out, 0, sizeof(float), stream);

    softmax_k<<<2 * B, 256, 0, stream>>>(ys, yt, ps, pt);
    cdist_k<<<dim3(16, 16), 1024, 0, stream>>>(ps, pt, Km);
    sink_k<<<NBLK, 512, 0, stream>>>(Km, sbuf, abuf, out);
}